// Round 1
// baseline (871.042 us; speedup 1.0000x reference)
//
#include <hip/hip_runtime.h>
#include <cstdint>
#include <cstddef>

#define DI __device__ __forceinline__

typedef __attribute__((ext_vector_type(8))) short bf16x8;   // 8 bf16 in 4 VGPRs
typedef __attribute__((ext_vector_type(4))) float f32x4;
using u16 = unsigned short;

struct Sel { int i0, i1; float g0, g1; };

DI u16 f2bf(float f) {
  union { float f; unsigned u; } c; c.f = f;
  unsigned u = c.u;
  unsigned r = (u + 0x7fffu + ((u >> 16) & 1u)) >> 16;   // RNE
  return (u16)r;
}

DI float softplus_f(float z) {
  return (z > 0.f) ? (z + log1pf(expf(-z))) : log1pf(expf(z));
}

DI void async16(const void* g, void* l) {
  __builtin_amdgcn_global_load_lds(
      (const __attribute__((address_space(1))) unsigned int*)g,
      (__attribute__((address_space(3))) unsigned int*)l, 16, 0, 0);
}

// ---------------------------------------------------------------------------
// Gating: per-token softplus(x . gn_e) partial sums + partial column-sums of x
// Block = 256 thr handles 64 tokens. Grid = 256 blocks (16384 tokens).
// ---------------------------------------------------------------------------
__global__ __launch_bounds__(256) void gate_kernel(
    const float* __restrict__ x, const float* __restrict__ gn,
    float* __restrict__ part_sp /*[256][64]*/, float* __restrict__ part_sx /*[256][1024]*/) {
  __shared__ float xs[8][1024];
  __shared__ float red[4][64];
  const int tid = threadIdx.x;
  const int tg = tid >> 6;        // 0..3 (wave id)
  const int e  = tid & 63;        // expert column
  const int tok0 = blockIdx.x * 64;
  float sx[4] = {0.f, 0.f, 0.f, 0.f};
  float spsum = 0.f;

  for (int it = 0; it < 8; ++it) {
    __syncthreads();
#pragma unroll
    for (int r = 0; r < 8; ++r)
      *(float4*)&xs[r][tid * 4] =
          *(const float4*)&x[(size_t)(tok0 + it * 8 + r) * 1024 + tid * 4];
    __syncthreads();
    // column sums of x (for the linear gate term)
#pragma unroll
    for (int j = 0; j < 4; ++j) {
      int i = tid + j * 256;
      float s = 0.f;
#pragma unroll
      for (int r = 0; r < 8; ++r) s += xs[r][i];
      sx[j] += s;
    }
    // two token dots per thread against gate_noise_w column e
    float d0 = 0.f, d1 = 0.f;
    for (int i = 0; i < 1024; i += 4) {
      float4 x0 = *(const float4*)&xs[tg][i];
      float4 x1 = *(const float4*)&xs[tg + 4][i];
#pragma unroll
      for (int j = 0; j < 4; ++j) {
        float wv = gn[(i + j) * 64 + e];
        d0 = fmaf(((const float*)&x0)[j], wv, d0);
        d1 = fmaf(((const float*)&x1)[j], wv, d1);
      }
    }
    spsum += softplus_f(d0) + softplus_f(d1);
  }
  red[tg][e] = spsum;
  __syncthreads();
  if (tid < 64)
    part_sp[blockIdx.x * 64 + tid] =
        red[0][tid] + red[1][tid] + red[2][tid] + red[3][tid];
#pragma unroll
  for (int j = 0; j < 4; ++j)
    part_sx[(size_t)blockIdx.x * 1024 + tid + j * 256] = sx[j];
}

// ---------------------------------------------------------------------------
// Selection: reduce partials, mean logits, top-2, gates, combined biases.
// One block, 256 threads. Deterministic (fixed-order reductions).
// ---------------------------------------------------------------------------
__global__ __launch_bounds__(256) void select_kernel(
    const float* __restrict__ part_sp, const float* __restrict__ part_sx,
    const float* __restrict__ gw, const float* __restrict__ noise,
    const float* __restrict__ bi, const float* __restrict__ bo,
    Sel* __restrict__ sel_out, float* __restrict__ bi_comb, float* __restrict__ bo_comb) {
  __shared__ float sx[1024];
  __shared__ float ml[64];
  __shared__ float red[256];
  __shared__ Sel sl;
  const int tid = threadIdx.x;
#pragma unroll
  for (int j = 0; j < 4; ++j) {
    int i = tid + j * 256;
    float s = 0.f;
    for (int b = 0; b < 256; ++b) s += part_sx[(size_t)b * 1024 + i];
    sx[i] = s;
  }
  float sp = 0.f;
  if (tid < 64)
    for (int b = 0; b < 256; ++b) sp += part_sp[b * 64 + tid];
  __syncthreads();
  {
    int e = tid & 63, q = tid >> 6;
    float d = 0.f;
    for (int i = q * 256; i < q * 256 + 256; ++i) d = fmaf(sx[i], gw[i * 64 + e], d);
    red[tid] = d;
  }
  __syncthreads();
  if (tid < 64)
    ml[tid] = (red[tid] + red[tid + 64] + red[tid + 128] + red[tid + 192] +
               sp * noise[tid]) * (1.f / 16384.f);
  __syncthreads();
  if (tid == 0) {
    int i0 = 0; float v0 = ml[0];
    for (int e2 = 1; e2 < 64; ++e2) if (ml[e2] > v0) { v0 = ml[e2]; i0 = e2; }
    int i1 = (i0 == 0) ? 1 : 0; float v1 = ml[i1];
    for (int e2 = 0; e2 < 64; ++e2)
      if (e2 != i0 && ml[e2] > v1) { v1 = ml[e2]; i1 = e2; }
    float e1 = expf(v1 - v0);                 // softmax over [v0, v1]
    float inv = 1.f / (1.f + e1);
    Sel s; s.i0 = i0; s.i1 = i1; s.g0 = inv; s.g1 = e1 * inv;
    sl = s; *sel_out = s;
  }
  __syncthreads();
  Sel s = sl;
  for (int n = tid; n < 2048; n += 256) {
    int ei = (n < 1024) ? s.i0 : s.i1;
    bi_comb[n] = bi[ei * 1024 + (n & 1023)];
  }
  for (int o = tid; o < 1024; o += 256)
    bo_comb[o] = s.g0 * bo[s.i0 * 1024 + o] + s.g1 * bo[s.i1 * 1024 + o];
}

// ---------------------------------------------------------------------------
// x (f32) -> bf16, vectorized
// ---------------------------------------------------------------------------
__global__ __launch_bounds__(256) void cvt_x(const float* __restrict__ x,
                                             u16* __restrict__ xb, int n4) {
  int i = blockIdx.x * 256 + threadIdx.x;
  const int stride = gridDim.x * 256;
  for (; i < n4; i += stride) {
    float4 v = ((const float4*)x)[i];
    ushort4 o; o.x = f2bf(v.x); o.y = f2bf(v.y); o.z = f2bf(v.z); o.w = f2bf(v.w);
    ((ushort4*)xb)[i] = o;
  }
}

// ---------------------------------------------------------------------------
// Transpose + bf16-convert selected expert weights.
// WiT[n][i]  = Wi[e_k][i][h]        (n = k*1024+h), [2048][1024]
// WoT[o][kc] = g_k * Wo[e_k][hh][o] (kc = k*1024+hh), [1024][2048]
// 1024 blocks of 256 thr; 64x64 tiles through LDS.
// ---------------------------------------------------------------------------
__global__ __launch_bounds__(256) void prep_weights(
    const float* __restrict__ Wi, const float* __restrict__ Wo,
    const Sel* __restrict__ selp, u16* __restrict__ WiT, u16* __restrict__ WoT) {
  __shared__ float tile[64][65];
  Sel s = *selp;
  const int bid = blockIdx.x;
  const float* src; float scale; u16* dst; int dld, dr0, dc0;
  if (bid < 512) {
    int tn = bid >> 4, ti = bid & 15;           // 32 n-tiles x 16 i-tiles
    int n0 = tn * 64, i0 = ti * 64;
    int k = n0 >> 10, h0 = n0 & 1023;
    int e = k ? s.i1 : s.i0;
    src = Wi + (size_t)e * 1024 * 1024 + (size_t)i0 * 1024 + h0; // [r=i][c=h]
    scale = 1.f; dst = WiT; dld = 1024; dr0 = n0; dc0 = i0;
  } else {
    int b2 = bid - 512;
    int ro = b2 >> 5, ck = b2 & 31;             // 16 o-tiles x 32 kc-tiles
    int o0 = ro * 64, kc0 = ck * 64;
    int k = kc0 >> 10, h0 = kc0 & 1023;
    int e = k ? s.i1 : s.i0;
    scale = k ? s.g1 : s.g0;
    src = Wo + (size_t)e * 1024 * 1024 + (size_t)h0 * 1024 + o0; // [r=hh][c=o]
    dst = WoT; dld = 2048; dr0 = o0; dc0 = kc0;
  }
  const int tid = threadIdx.x;
#pragma unroll
  for (int j = 0; j < 4; ++j) {
    int lin = j * 256 + tid;
    int r = lin >> 4, c4 = (lin & 15) * 4;
    float4 v = *(const float4*)&src[(size_t)r * 1024 + c4];
    tile[r][c4] = v.x; tile[r][c4 + 1] = v.y; tile[r][c4 + 2] = v.z; tile[r][c4 + 3] = v.w;
  }
  __syncthreads();
#pragma unroll
  for (int j = 0; j < 4; ++j) {
    int lin = j * 256 + tid;
    int r2 = lin >> 4, c2 = (lin & 15) * 4;     // r2: out row, c2: out col
    ushort4 o;
    o.x = f2bf(scale * tile[c2][r2]);
    o.y = f2bf(scale * tile[c2 + 1][r2]);
    o.z = f2bf(scale * tile[c2 + 2][r2]);
    o.w = f2bf(scale * tile[c2 + 3][r2]);
    *(ushort4*)&dst[(size_t)(dr0 + r2) * dld + dc0 + c2] = o;
  }
}

// ---------------------------------------------------------------------------
// bf16 GEMM, B pre-transposed ([N][K]). m97 structure: 128x128 tile, BK=64,
// 4 waves (2x2), 16x16x32 MFMA, global_load_lds width 16, 2-barrier K-loop.
// C = act(A @ Bt^T + bias)
// ---------------------------------------------------------------------------
template <int RELU, typename OUTT>
__global__ __launch_bounds__(256) void gemm_bt(
    const u16* __restrict__ A, const u16* __restrict__ Bt,
    const float* __restrict__ bias, OUTT* __restrict__ C, int N, int K) {
  __shared__ u16 smA[128 * 64];
  __shared__ u16 smB[128 * 64];
  const int tid = threadIdx.x;
  const int wave = tid >> 6, lane = tid & 63;
  const int m0 = blockIdx.y * 128, n0 = blockIdx.x * 128;
  const int wm = wave >> 1, wn = wave & 1;

  f32x4 acc[4][4] = {};

  const u16* gA = A + (size_t)(m0 + wave * 8 + (lane >> 3)) * K + (lane & 7) * 8;
  const u16* gB = Bt + (size_t)(n0 + wave * 8 + (lane >> 3)) * K + (lane & 7) * 8;
  u16* lA = smA + wave * 512;   // wave-uniform LDS staging base
  u16* lB = smB + wave * 512;

  for (int kt = 0; kt < K; kt += 64) {
#pragma unroll
    for (int j = 0; j < 4; ++j) {
      async16(gA + (size_t)j * 32 * K + kt, lA + j * 2048);
      async16(gB + (size_t)j * 32 * K + kt, lB + j * 2048);
    }
    __syncthreads();                      // drains vmcnt: tiles ready
#pragma unroll
    for (int kk = 0; kk < 2; ++kk) {
      bf16x8 af[4], bfr[4];
#pragma unroll
      for (int m = 0; m < 4; ++m)
        af[m] = *(const bf16x8*)(smA + (wm * 64 + m * 16 + (lane & 15)) * 64 +
                                 kk * 32 + (lane >> 4) * 8);
#pragma unroll
      for (int n = 0; n < 4; ++n)
        bfr[n] = *(const bf16x8*)(smB + (wn * 64 + n * 16 + (lane & 15)) * 64 +
                                  kk * 32 + (lane >> 4) * 8);
#pragma unroll
      for (int m = 0; m < 4; ++m)
#pragma unroll
        for (int n = 0; n < 4; ++n)
          acc[m][n] = __builtin_amdgcn_mfma_f32_16x16x32_bf16(af[m], bfr[n], acc[m][n], 0, 0, 0);
    }
    __syncthreads();                      // all reads done before next stage
  }

  const int r0 = m0 + wm * 64 + (lane >> 4) * 4;
  const int c0 = n0 + wn * 64 + (lane & 15);
#pragma unroll
  for (int n = 0; n < 4; ++n) {
    int col = c0 + n * 16;
    float bv = bias[col];
#pragma unroll
    for (int m = 0; m < 4; ++m) {
#pragma unroll
      for (int r = 0; r < 4; ++r) {
        int row = r0 + m * 16 + r;
        float v = acc[m][n][r] + bv;
        if (RELU) v = fmaxf(v, 0.f);
        if constexpr (sizeof(OUTT) == 2)
          C[(size_t)row * N + col] = f2bf(v);
        else
          C[(size_t)row * N + col] = v;
      }
    }
  }
}

// ---------------------------------------------------------------------------
extern "C" void kernel_launch(void* const* d_in, const int* in_sizes, int n_in,
                              void* d_out, int out_size, void* d_ws, size_t ws_size,
                              hipStream_t stream) {
  const float* x     = (const float*)d_in[0];
  const float* noise = (const float*)d_in[1];
  const float* gw    = (const float*)d_in[2];
  const float* gn    = (const float*)d_in[3];
  const float* Wi    = (const float*)d_in[4];
  const float* bi    = (const float*)d_in[5];
  const float* Wo    = (const float*)d_in[6];
  const float* bo    = (const float*)d_in[7];
  float* out = (float*)d_out;

  char* w = (char*)d_ws;
  float* part_sp = (float*)(w + 0x000000);       //  64 KB: [256][64]
  float* part_sx = (float*)(w + 0x010000);       //   1 MB: [256][1024]
  Sel*   sel     = (Sel*)  (w + 0x110000);       //   16 B
  float* bi_comb = (float*)(w + 0x110100);       //   8 KB
  float* bo_comb = (float*)(w + 0x112100);       //   4 KB
  u16*   xb      = (u16*)  (w + 0x0200000);      //  32 MB: [16384][1024]
  u16*   WiT     = (u16*)  (w + 0x2200000);      //   4 MB: [2048][1024]
  u16*   WoT     = (u16*)  (w + 0x2600000);      //   4 MB: [1024][2048]
  u16*   h       = (u16*)  (w + 0x2A00000);      //  64 MB: [16384][2048]

  cvt_x<<<2048, 256, 0, stream>>>(x, xb, 16384 * 1024 / 4);
  gate_kernel<<<256, 256, 0, stream>>>(x, gn, part_sp, part_sx);
  select_kernel<<<1, 256, 0, stream>>>(part_sp, part_sx, gw, noise, bi, bo,
                                       sel, bi_comb, bo_comb);
  prep_weights<<<1024, 256, 0, stream>>>(Wi, Wo, sel, WiT, WoT);
  gemm_bt<1, u16>  <<<dim3(16, 128), 256, 0, stream>>>(xb, WiT, bi_comb, h, 2048, 1024);
  gemm_bt<0, float><<<dim3(8, 128), 256, 0, stream>>>(h, WoT, bo_comb, out, 1024, 2048);
}

// Round 2
// 411.386 us; speedup vs baseline: 2.1173x; 2.1173x over previous
//
#include <hip/hip_runtime.h>
#include <cstdint>
#include <cstddef>

#define DI __device__ __forceinline__

typedef __attribute__((ext_vector_type(8))) short bf16x8;   // 8 bf16 in 4 VGPRs
typedef __attribute__((ext_vector_type(4))) float f32x4;
using u16 = unsigned short;

struct Sel { int i0, i1; float g0, g1; };

DI u16 f2bf(float f) {
  union { float f; unsigned u; } c; c.f = f;
  unsigned u = c.u;
  unsigned r = (u + 0x7fffu + ((u >> 16) & 1u)) >> 16;   // RNE
  return (u16)r;
}

DI float bf2f(u16 h) {
  union { unsigned u; float f; } c; c.u = ((unsigned)h) << 16; return c.f;
}

DI float softplus_f(float z) {
  return (z > 0.f) ? (z + log1pf(expf(-z))) : log1pf(expf(z));
}

DI void async16(const void* g, void* l) {
  __builtin_amdgcn_global_load_lds(
      (const __attribute__((address_space(1))) unsigned int*)g,
      (__attribute__((address_space(3))) unsigned int*)l, 16, 0, 0);
}

// ---------------------------------------------------------------------------
// cvt: x (f32) -> bf16 [256 blocks, 64 rows each] ; gn (f32) -> gnT bf16 [16 blocks]
// ---------------------------------------------------------------------------
__global__ __launch_bounds__(256) void cvt_x_gn(
    const float* __restrict__ x, const float* __restrict__ gn,
    u16* __restrict__ xb, u16* __restrict__ gnT) {
  const int tid = threadIdx.x;
  if (blockIdx.x < 256) {
    const int r0 = blockIdx.x * 64;
    const int c4 = tid * 4;
#pragma unroll 4
    for (int r = 0; r < 64; ++r) {
      float4 v = *(const float4*)&x[(size_t)(r0 + r) * 1024 + c4];
      ushort4 o; o.x = f2bf(v.x); o.y = f2bf(v.y); o.z = f2bf(v.z); o.w = f2bf(v.w);
      *(ushort4*)&xb[(size_t)(r0 + r) * 1024 + c4] = o;
    }
  } else {
    // transpose one 64(i) x 64(e) tile of gn into gnT[e][i]
    __shared__ float tile[64][65];
    const int i0 = (blockIdx.x - 256) * 64;
#pragma unroll
    for (int j = 0; j < 16; ++j) {
      int lin = j * 256 + tid;
      int r = lin >> 6, c = lin & 63;
      tile[r][c] = gn[(size_t)(i0 + r) * 64 + c];
    }
    __syncthreads();
#pragma unroll
    for (int j = 0; j < 16; ++j) {
      int lin = j * 256 + tid;
      int e = lin >> 6, r2 = lin & 63;
      gnT[(size_t)e * 1024 + i0 + r2] = f2bf(tile[r2][e]);
    }
  }
}

// ---------------------------------------------------------------------------
// Gate via MFMA: logits_n = xb @ gnT^T  [64-token tile x 64 experts], then
// softplus + column-reduce -> part_sp[256][64]. Also f32 column-sums of the
// staged x tile -> part_sx[256][1024] (for the exact linear gate term).
// 256 blocks x 256 thr (4 waves, 16 token-rows each). K = 1024, BK = 64.
// ---------------------------------------------------------------------------
__global__ __launch_bounds__(256) void gate_mfma(
    const u16* __restrict__ xb, const u16* __restrict__ gnT,
    float* __restrict__ part_sp, float* __restrict__ part_sx) {
  __shared__ u16 smX[64 * 64];
  __shared__ u16 smG[64 * 64];
  __shared__ float colsum[4][1024];
  __shared__ float red[4][64];
  const int tid = threadIdx.x;
  const int wave = tid >> 6, lane = tid & 63;
  const int m0 = blockIdx.x * 64;

  f32x4 acc[4] = {};

  const u16* gA = xb + (size_t)(m0 + wave * 8 + (lane >> 3)) * 1024 + (lane & 7) * 8;
  const u16* gG = gnT + (size_t)(wave * 8 + (lane >> 3)) * 1024 + (lane & 7) * 8;
  u16* lX = smX + wave * 512;
  u16* lG = smG + wave * 512;

  for (int kt = 0; kt < 1024; kt += 64) {
#pragma unroll
    for (int j = 0; j < 2; ++j) {
      async16(gA + (size_t)j * 32 * 1024 + kt, lX + j * 2048);
      async16(gG + (size_t)j * 32 * 1024 + kt, lG + j * 2048);
    }
    __syncthreads();
    // MFMA on the tile
#pragma unroll
    for (int kk = 0; kk < 2; ++kk) {
      bf16x8 af = *(const bf16x8*)(smX + (wave * 16 + (lane & 15)) * 64 +
                                   kk * 32 + (lane >> 4) * 8);
#pragma unroll
      for (int n = 0; n < 4; ++n) {
        bf16x8 bfr = *(const bf16x8*)(smG + (n * 16 + (lane & 15)) * 64 +
                                      kk * 32 + (lane >> 4) * 8);
        acc[n] = __builtin_amdgcn_mfma_f32_16x16x32_bf16(af, bfr, acc[n], 0, 0, 0);
      }
    }
    // f32 column partial sums of this x tile (16 rows per wave, col = lane)
    {
      float s = 0.f;
      const int rb = wave * 16;
#pragma unroll
      for (int r = 0; r < 16; ++r) s += bf2f(smX[(rb + r) * 64 + lane]);
      colsum[wave][kt + lane] = s;
    }
    __syncthreads();
  }

  // softplus + reduce over the wave's 16 token rows per expert column
#pragma unroll
  for (int n = 0; n < 4; ++n) {
    float s = softplus_f(acc[n][0]) + softplus_f(acc[n][1]) +
              softplus_f(acc[n][2]) + softplus_f(acc[n][3]);
    s += __shfl_xor(s, 16);
    s += __shfl_xor(s, 32);
    if (lane < 16) red[wave][n * 16 + lane] = s;
  }
  __syncthreads();
  if (tid < 64)
    part_sp[(size_t)blockIdx.x * 64 + tid] =
        red[0][tid] + red[1][tid] + red[2][tid] + red[3][tid];
#pragma unroll
  for (int j = 0; j < 4; ++j) {
    int i = tid + j * 256;
    part_sx[(size_t)blockIdx.x * 1024 + i] =
        colsum[0][i] + colsum[1][i] + colsum[2][i] + colsum[3][i];
  }
}

// ---------------------------------------------------------------------------
// Selection: reduce partials, mean logits, top-2, gates, combined biases.
// One block, 256 threads. Deterministic (fixed-order reductions).
// ---------------------------------------------------------------------------
__global__ __launch_bounds__(256) void select_kernel(
    const float* __restrict__ part_sp, const float* __restrict__ part_sx,
    const float* __restrict__ gw, const float* __restrict__ noise,
    const float* __restrict__ bi, const float* __restrict__ bo,
    Sel* __restrict__ sel_out, float* __restrict__ bi_comb, float* __restrict__ bo_comb) {
  __shared__ float sx[1024];
  __shared__ float ml[64];
  __shared__ float red[256];
  __shared__ Sel sl;
  const int tid = threadIdx.x;
#pragma unroll
  for (int j = 0; j < 4; ++j) {
    int i = tid + j * 256;
    float s = 0.f;
    for (int b = 0; b < 256; ++b) s += part_sx[(size_t)b * 1024 + i];
    sx[i] = s;
  }
  float sp = 0.f;
  if (tid < 64)
    for (int b = 0; b < 256; ++b) sp += part_sp[b * 64 + tid];
  __syncthreads();
  {
    int e = tid & 63, q = tid >> 6;
    float d = 0.f;
    for (int i = q * 256; i < q * 256 + 256; ++i) d = fmaf(sx[i], gw[i * 64 + e], d);
    red[tid] = d;
  }
  __syncthreads();
  if (tid < 64)
    ml[tid] = (red[tid] + red[tid + 64] + red[tid + 128] + red[tid + 192] +
               sp * noise[tid]) * (1.f / 16384.f);
  __syncthreads();
  if (tid == 0) {
    int i0 = 0; float v0 = ml[0];
    for (int e2 = 1; e2 < 64; ++e2) if (ml[e2] > v0) { v0 = ml[e2]; i0 = e2; }
    int i1 = (i0 == 0) ? 1 : 0; float v1 = ml[i1];
    for (int e2 = 0; e2 < 64; ++e2)
      if (e2 != i0 && ml[e2] > v1) { v1 = ml[e2]; i1 = e2; }
    float e1 = expf(v1 - v0);                 // softmax over [v0, v1]
    float inv = 1.f / (1.f + e1);
    Sel s; s.i0 = i0; s.i1 = i1; s.g0 = inv; s.g1 = e1 * inv;
    sl = s; *sel_out = s;
  }
  __syncthreads();
  Sel s = sl;
  for (int n = tid; n < 2048; n += 256) {
    int ei = (n < 1024) ? s.i0 : s.i1;
    bi_comb[n] = bi[ei * 1024 + (n & 1023)];
  }
  for (int o = tid; o < 1024; o += 256)
    bo_comb[o] = s.g0 * bo[s.i0 * 1024 + o] + s.g1 * bo[s.i1 * 1024 + o];
}

// ---------------------------------------------------------------------------
// Transpose + bf16-convert selected expert weights.
// WiT[n][i]  = Wi[e_k][i][h]        (n = k*1024+h), [2048][1024]
// WoT[o][kc] = g_k * Wo[e_k][hh][o] (kc = k*1024+hh), [1024][2048]
// 1024 blocks of 256 thr; 64x64 tiles through LDS.
// ---------------------------------------------------------------------------
__global__ __launch_bounds__(256) void prep_weights(
    const float* __restrict__ Wi, const float* __restrict__ Wo,
    const Sel* __restrict__ selp, u16* __restrict__ WiT, u16* __restrict__ WoT) {
  __shared__ float tile[64][65];
  Sel s = *selp;
  const int bid = blockIdx.x;
  const float* src; float scale; u16* dst; int dld, dr0, dc0;
  if (bid < 512) {
    int tn = bid >> 4, ti = bid & 15;           // 32 n-tiles x 16 i-tiles
    int n0 = tn * 64, i0 = ti * 64;
    int k = n0 >> 10, h0 = n0 & 1023;
    int e = k ? s.i1 : s.i0;
    src = Wi + (size_t)e * 1024 * 1024 + (size_t)i0 * 1024 + h0; // [r=i][c=h]
    scale = 1.f; dst = WiT; dld = 1024; dr0 = n0; dc0 = i0;
  } else {
    int b2 = bid - 512;
    int ro = b2 >> 5, ck = b2 & 31;             // 16 o-tiles x 32 kc-tiles
    int o0 = ro * 64, kc0 = ck * 64;
    int k = kc0 >> 10, h0 = kc0 & 1023;
    int e = k ? s.i1 : s.i0;
    scale = k ? s.g1 : s.g0;
    src = Wo + (size_t)e * 1024 * 1024 + (size_t)h0 * 1024 + o0; // [r=hh][c=o]
    dst = WoT; dld = 2048; dr0 = o0; dc0 = kc0;
  }
  const int tid = threadIdx.x;
#pragma unroll
  for (int j = 0; j < 4; ++j) {
    int lin = j * 256 + tid;
    int r = lin >> 4, c4 = (lin & 15) * 4;
    float4 v = *(const float4*)&src[(size_t)r * 1024 + c4];
    tile[r][c4] = v.x; tile[r][c4 + 1] = v.y; tile[r][c4 + 2] = v.z; tile[r][c4 + 3] = v.w;
  }
  __syncthreads();
#pragma unroll
  for (int j = 0; j < 4; ++j) {
    int lin = j * 256 + tid;
    int r2 = lin >> 4, c2 = (lin & 15) * 4;     // r2: out row, c2: out col
    ushort4 o;
    o.x = f2bf(scale * tile[c2][r2]);
    o.y = f2bf(scale * tile[c2 + 1][r2]);
    o.z = f2bf(scale * tile[c2 + 2][r2]);
    o.w = f2bf(scale * tile[c2 + 3][r2]);
    *(ushort4*)&dst[(size_t)(dr0 + r2) * dld + dc0 + c2] = o;
  }
}

// ---------------------------------------------------------------------------
// bf16 GEMM, B pre-transposed ([N][K]). m97 structure: 128x128 tile, BK=64,
// 4 waves (2x2), 16x16x32 MFMA, global_load_lds width 16, 2-barrier K-loop.
// C = act(A @ Bt^T + bias)
// ---------------------------------------------------------------------------
template <int RELU, typename OUTT>
__global__ __launch_bounds__(256) void gemm_bt(
    const u16* __restrict__ A, const u16* __restrict__ Bt,
    const float* __restrict__ bias, OUTT* __restrict__ C, int N, int K) {
  __shared__ u16 smA[128 * 64];
  __shared__ u16 smB[128 * 64];
  const int tid = threadIdx.x;
  const int wave = tid >> 6, lane = tid & 63;
  const int m0 = blockIdx.y * 128, n0 = blockIdx.x * 128;
  const int wm = wave >> 1, wn = wave & 1;

  f32x4 acc[4][4] = {};

  const u16* gA = A + (size_t)(m0 + wave * 8 + (lane >> 3)) * K + (lane & 7) * 8;
  const u16* gB = Bt + (size_t)(n0 + wave * 8 + (lane >> 3)) * K + (lane & 7) * 8;
  u16* lA = smA + wave * 512;   // wave-uniform LDS staging base
  u16* lB = smB + wave * 512;

  for (int kt = 0; kt < K; kt += 64) {
#pragma unroll
    for (int j = 0; j < 4; ++j) {
      async16(gA + (size_t)j * 32 * K + kt, lA + j * 2048);
      async16(gB + (size_t)j * 32 * K + kt, lB + j * 2048);
    }
    __syncthreads();                      // drains vmcnt: tiles ready
#pragma unroll
    for (int kk = 0; kk < 2; ++kk) {
      bf16x8 af[4], bfr[4];
#pragma unroll
      for (int m = 0; m < 4; ++m)
        af[m] = *(const bf16x8*)(smA + (wm * 64 + m * 16 + (lane & 15)) * 64 +
                                 kk * 32 + (lane >> 4) * 8);
#pragma unroll
      for (int n = 0; n < 4; ++n)
        bfr[n] = *(const bf16x8*)(smB + (wn * 64 + n * 16 + (lane & 15)) * 64 +
                                  kk * 32 + (lane >> 4) * 8);
#pragma unroll
      for (int m = 0; m < 4; ++m)
#pragma unroll
        for (int n = 0; n < 4; ++n)
          acc[m][n] = __builtin_amdgcn_mfma_f32_16x16x32_bf16(af[m], bfr[n], acc[m][n], 0, 0, 0);
    }
    __syncthreads();                      // all reads done before next stage
  }

  const int r0 = m0 + wm * 64 + (lane >> 4) * 4;
  const int c0 = n0 + wn * 64 + (lane & 15);
#pragma unroll
  for (int n = 0; n < 4; ++n) {
    int col = c0 + n * 16;
    float bv = bias[col];
#pragma unroll
    for (int m = 0; m < 4; ++m) {
#pragma unroll
      for (int r = 0; r < 4; ++r) {
        int row = r0 + m * 16 + r;
        float v = acc[m][n][r] + bv;
        if (RELU) v = fmaxf(v, 0.f);
        if constexpr (sizeof(OUTT) == 2)
          C[(size_t)row * N + col] = f2bf(v);
        else
          C[(size_t)row * N + col] = v;
      }
    }
  }
}

// ---------------------------------------------------------------------------
extern "C" void kernel_launch(void* const* d_in, const int* in_sizes, int n_in,
                              void* d_out, int out_size, void* d_ws, size_t ws_size,
                              hipStream_t stream) {
  const float* x     = (const float*)d_in[0];
  const float* noise = (const float*)d_in[1];
  const float* gw    = (const float*)d_in[2];
  const float* gn    = (const float*)d_in[3];
  const float* Wi    = (const float*)d_in[4];
  const float* bi    = (const float*)d_in[5];
  const float* Wo    = (const float*)d_in[6];
  const float* bo    = (const float*)d_in[7];
  float* out = (float*)d_out;

  char* w = (char*)d_ws;
  float* part_sp = (float*)(w + 0x000000);       //  64 KB: [256][64]
  float* part_sx = (float*)(w + 0x010000);       //   1 MB: [256][1024]
  Sel*   sel     = (Sel*)  (w + 0x110000);       //   16 B
  float* bi_comb = (float*)(w + 0x110100);       //   8 KB
  float* bo_comb = (float*)(w + 0x112100);       //   4 KB
  u16*   gnT     = (u16*)  (w + 0x120000);       // 128 KB: [64][1024]
  u16*   xb      = (u16*)  (w + 0x0200000);      //  32 MB: [16384][1024]
  u16*   WiT     = (u16*)  (w + 0x2200000);      //   4 MB: [2048][1024]
  u16*   WoT     = (u16*)  (w + 0x2600000);      //   4 MB: [1024][2048]
  u16*   h       = (u16*)  (w + 0x2A00000);      //  64 MB: [16384][2048]

  cvt_x_gn<<<272, 256, 0, stream>>>(x, gn, xb, gnT);
  gate_mfma<<<256, 256, 0, stream>>>(xb, gnT, part_sp, part_sx);
  select_kernel<<<1, 256, 0, stream>>>(part_sp, part_sx, gw, noise, bi, bo,
                                       sel, bi_comb, bo_comb);
  prep_weights<<<1024, 256, 0, stream>>>(Wi, Wo, sel, WiT, WoT);
  gemm_bt<1, u16>  <<<dim3(16, 128), 256, 0, stream>>>(xb, WiT, bi_comb, h, 2048, 1024);
  gemm_bt<0, float><<<dim3(8, 128), 256, 0, stream>>>(h, WoT, bo_comb, out, 1024, 2048);
}

// Round 3
// 267.365 us; speedup vs baseline: 3.2579x; 1.5387x over previous
//
#include <hip/hip_runtime.h>
#include <cstdint>
#include <cstddef>

#define DI __device__ __forceinline__

typedef __attribute__((ext_vector_type(8))) short bf16x8;   // 8 bf16 in 4 VGPRs
typedef __attribute__((ext_vector_type(4))) float f32x4;
using u16 = unsigned short;

struct Sel { int i0, i1; float g0, g1; };

DI u16 f2bf(float f) {
  union { float f; unsigned u; } c; c.f = f;
  unsigned u = c.u;
  unsigned r = (u + 0x7fffu + ((u >> 16) & 1u)) >> 16;   // RNE
  return (u16)r;
}

DI float bf2f(u16 h) {
  union { unsigned u; float f; } c; c.u = ((unsigned)h) << 16; return c.f;
}

DI float softplus_f(float z) {
  return (z > 0.f) ? (z + log1pf(expf(-z))) : log1pf(expf(z));
}

DI void async16(const void* g, void* l) {
  __builtin_amdgcn_global_load_lds(
      (const __attribute__((address_space(1))) unsigned int*)g,
      (__attribute__((address_space(3))) unsigned int*)l, 16, 0, 0);
}

// ---------------------------------------------------------------------------
// cvt: x (f32) -> bf16 [256 blocks, 64 rows each] ; gn (f32) -> gnT bf16 [16 blocks]
// ---------------------------------------------------------------------------
__global__ __launch_bounds__(256) void cvt_x_gn(
    const float* __restrict__ x, const float* __restrict__ gn,
    u16* __restrict__ xb, u16* __restrict__ gnT) {
  const int tid = threadIdx.x;
  if (blockIdx.x < 256) {
    const int r0 = blockIdx.x * 64;
    const int c4 = tid * 4;
#pragma unroll 4
    for (int r = 0; r < 64; ++r) {
      float4 v = *(const float4*)&x[(size_t)(r0 + r) * 1024 + c4];
      ushort4 o; o.x = f2bf(v.x); o.y = f2bf(v.y); o.z = f2bf(v.z); o.w = f2bf(v.w);
      *(ushort4*)&xb[(size_t)(r0 + r) * 1024 + c4] = o;
    }
  } else {
    // transpose one 64(i) x 64(e) tile of gn into gnT[e][i]
    __shared__ float tile[64][65];
    const int i0 = (blockIdx.x - 256) * 64;
#pragma unroll
    for (int j = 0; j < 16; ++j) {
      int lin = j * 256 + tid;
      int r = lin >> 6, c = lin & 63;
      tile[r][c] = gn[(size_t)(i0 + r) * 64 + c];
    }
    __syncthreads();
#pragma unroll
    for (int j = 0; j < 16; ++j) {
      int lin = j * 256 + tid;
      int e = lin >> 6, r2 = lin & 63;
      gnT[(size_t)e * 1024 + i0 + r2] = f2bf(tile[r2][e]);
    }
  }
}

// ---------------------------------------------------------------------------
// Gate via MFMA: logits_n = xb @ gnT^T  [64-token tile x 64 experts], then
// softplus + column-reduce -> part_sp[256][64]. Also f32 column-sums of the
// staged x tile -> part_sx[256][1024] (for the exact linear gate term).
// ---------------------------------------------------------------------------
__global__ __launch_bounds__(256) void gate_mfma(
    const u16* __restrict__ xb, const u16* __restrict__ gnT,
    float* __restrict__ part_sp, float* __restrict__ part_sx) {
  __shared__ u16 smX[64 * 64];
  __shared__ u16 smG[64 * 64];
  __shared__ float colsum[4][1024];
  __shared__ float red[4][64];
  const int tid = threadIdx.x;
  const int wave = tid >> 6, lane = tid & 63;
  const int m0 = blockIdx.x * 64;

  f32x4 acc[4] = {};

  const u16* gA = xb + (size_t)(m0 + wave * 8 + (lane >> 3)) * 1024 + (lane & 7) * 8;
  const u16* gG = gnT + (size_t)(wave * 8 + (lane >> 3)) * 1024 + (lane & 7) * 8;
  u16* lX = smX + wave * 512;
  u16* lG = smG + wave * 512;

  for (int kt = 0; kt < 1024; kt += 64) {
#pragma unroll
    for (int j = 0; j < 2; ++j) {
      async16(gA + (size_t)j * 32 * 1024 + kt, lX + j * 2048);
      async16(gG + (size_t)j * 32 * 1024 + kt, lG + j * 2048);
    }
    __syncthreads();
#pragma unroll
    for (int kk = 0; kk < 2; ++kk) {
      bf16x8 af = *(const bf16x8*)(smX + (wave * 16 + (lane & 15)) * 64 +
                                   kk * 32 + (lane >> 4) * 8);
#pragma unroll
      for (int n = 0; n < 4; ++n) {
        bf16x8 bfr = *(const bf16x8*)(smG + (n * 16 + (lane & 15)) * 64 +
                                      kk * 32 + (lane >> 4) * 8);
        acc[n] = __builtin_amdgcn_mfma_f32_16x16x32_bf16(af, bfr, acc[n], 0, 0, 0);
      }
    }
    // f32 column partial sums of this x tile (16 rows per wave, col = lane)
    {
      float s = 0.f;
      const int rb = wave * 16;
#pragma unroll
      for (int r = 0; r < 16; ++r) s += bf2f(smX[(rb + r) * 64 + lane]);
      colsum[wave][kt + lane] = s;
    }
    __syncthreads();
  }

#pragma unroll
  for (int n = 0; n < 4; ++n) {
    float s = softplus_f(acc[n][0]) + softplus_f(acc[n][1]) +
              softplus_f(acc[n][2]) + softplus_f(acc[n][3]);
    s += __shfl_xor(s, 16);
    s += __shfl_xor(s, 32);
    if (lane < 16) red[wave][n * 16 + lane] = s;
  }
  __syncthreads();
  if (tid < 64)
    part_sp[(size_t)blockIdx.x * 64 + tid] =
        red[0][tid] + red[1][tid] + red[2][tid] + red[3][tid];
#pragma unroll
  for (int j = 0; j < 4; ++j) {
    int i = tid + j * 256;
    part_sx[(size_t)blockIdx.x * 1024 + i] =
        colsum[0][i] + colsum[1][i] + colsum[2][i] + colsum[3][i];
  }
}

// ---------------------------------------------------------------------------
// Mid-level reduction: 256 partials -> 32 partials, fully parallel.
// 32 blocks x 256 thr; block bb reduces b in [bb*8, bb*8+8).
// ---------------------------------------------------------------------------
__global__ __launch_bounds__(256) void reduce_parts(
    const float* __restrict__ part_sp, const float* __restrict__ part_sx,
    float* __restrict__ p2_sp, float* __restrict__ p2_sx) {
  const int bb = blockIdx.x, tid = threadIdx.x;
  const int b0 = bb * 8;
#pragma unroll
  for (int j = 0; j < 4; ++j) {
    int i = tid + j * 256;
    float s = 0.f;
#pragma unroll
    for (int b = 0; b < 8; ++b) s += part_sx[(size_t)(b0 + b) * 1024 + i];
    p2_sx[(size_t)bb * 1024 + i] = s;
  }
  if (tid < 64) {
    float s = 0.f;
#pragma unroll
    for (int b = 0; b < 8; ++b) s += part_sp[(b0 + b) * 64 + tid];
    p2_sp[bb * 64 + tid] = s;
  }
}

// ---------------------------------------------------------------------------
// Selection: reduce 32 partials, mean logits, top-2, gates, combined biases.
// One block, 256 threads. ILP-pipelined loads (multiple accumulator chains).
// ---------------------------------------------------------------------------
__global__ __launch_bounds__(256) void select_kernel(
    const float* __restrict__ p2_sp, const float* __restrict__ p2_sx,
    const float* __restrict__ gw, const float* __restrict__ noise,
    const float* __restrict__ bi, const float* __restrict__ bo,
    Sel* __restrict__ sel_out, float* __restrict__ bi_comb, float* __restrict__ bo_comb) {
  __shared__ float sx[1024];
  __shared__ float ml[64];
  __shared__ float red[256];
  __shared__ Sel sl;
  const int tid = threadIdx.x;
#pragma unroll
  for (int j = 0; j < 4; ++j) {
    int i = tid + j * 256;
    float s0 = 0.f, s1 = 0.f, s2 = 0.f, s3 = 0.f;
#pragma unroll
    for (int b = 0; b < 32; b += 4) {
      s0 += p2_sx[(size_t)(b + 0) * 1024 + i];
      s1 += p2_sx[(size_t)(b + 1) * 1024 + i];
      s2 += p2_sx[(size_t)(b + 2) * 1024 + i];
      s3 += p2_sx[(size_t)(b + 3) * 1024 + i];
    }
    sx[i] = (s0 + s1) + (s2 + s3);
  }
  float sp = 0.f;
  if (tid < 64) {
    float s0 = 0.f, s1 = 0.f, s2 = 0.f, s3 = 0.f;
#pragma unroll
    for (int b = 0; b < 32; b += 4) {
      s0 += p2_sp[(b + 0) * 64 + tid];
      s1 += p2_sp[(b + 1) * 64 + tid];
      s2 += p2_sp[(b + 2) * 64 + tid];
      s3 += p2_sp[(b + 3) * 64 + tid];
    }
    sp = (s0 + s1) + (s2 + s3);
  }
  __syncthreads();
  {
    int e = tid & 63, q = tid >> 6;
    const float* gwq = gw + (size_t)(q * 256) * 64 + e;
    const float* sxq = sx + q * 256;
    float d0 = 0.f, d1 = 0.f, d2 = 0.f, d3 = 0.f;
#pragma unroll 8
    for (int i = 0; i < 256; i += 4) {
      d0 = fmaf(sxq[i + 0], gwq[(i + 0) * 64], d0);
      d1 = fmaf(sxq[i + 1], gwq[(i + 1) * 64], d1);
      d2 = fmaf(sxq[i + 2], gwq[(i + 2) * 64], d2);
      d3 = fmaf(sxq[i + 3], gwq[(i + 3) * 64], d3);
    }
    red[tid] = (d0 + d1) + (d2 + d3);
  }
  __syncthreads();
  if (tid < 64)
    ml[tid] = (red[tid] + red[tid + 64] + red[tid + 128] + red[tid + 192] +
               sp * noise[tid]) * (1.f / 16384.f);
  __syncthreads();
  if (tid == 0) {
    int i0 = 0; float v0 = ml[0];
    for (int e2 = 1; e2 < 64; ++e2) if (ml[e2] > v0) { v0 = ml[e2]; i0 = e2; }
    int i1 = (i0 == 0) ? 1 : 0; float v1 = ml[i1];
    for (int e2 = 0; e2 < 64; ++e2)
      if (e2 != i0 && ml[e2] > v1) { v1 = ml[e2]; i1 = e2; }
    float e1 = expf(v1 - v0);                 // softmax over [v0, v1]
    float inv = 1.f / (1.f + e1);
    Sel s; s.i0 = i0; s.i1 = i1; s.g0 = inv; s.g1 = e1 * inv;
    sl = s; *sel_out = s;
  }
  __syncthreads();
  Sel s = sl;
  for (int n = tid; n < 2048; n += 256) {
    int ei = (n < 1024) ? s.i0 : s.i1;
    bi_comb[n] = bi[ei * 1024 + (n & 1023)];
  }
  for (int o = tid; o < 1024; o += 256)
    bo_comb[o] = s.g0 * bo[s.i0 * 1024 + o] + s.g1 * bo[s.i1 * 1024 + o];
}

// ---------------------------------------------------------------------------
// Transpose + bf16-convert selected expert weights.
// WiT[n][i]  = Wi[e_k][i][h]        (n = k*1024+h), [2048][1024]
// WoT[o][kc] = g_k * Wo[e_k][hh][o] (kc = k*1024+hh), [1024][2048]
// ---------------------------------------------------------------------------
__global__ __launch_bounds__(256) void prep_weights(
    const float* __restrict__ Wi, const float* __restrict__ Wo,
    const Sel* __restrict__ selp, u16* __restrict__ WiT, u16* __restrict__ WoT) {
  __shared__ float tile[64][65];
  Sel s = *selp;
  const int bid = blockIdx.x;
  const float* src; float scale; u16* dst; int dld, dr0, dc0;
  if (bid < 512) {
    int tn = bid >> 4, ti = bid & 15;           // 32 n-tiles x 16 i-tiles
    int n0 = tn * 64, i0 = ti * 64;
    int k = n0 >> 10, h0 = n0 & 1023;
    int e = k ? s.i1 : s.i0;
    src = Wi + (size_t)e * 1024 * 1024 + (size_t)i0 * 1024 + h0; // [r=i][c=h]
    scale = 1.f; dst = WiT; dld = 1024; dr0 = n0; dc0 = i0;
  } else {
    int b2 = bid - 512;
    int ro = b2 >> 5, ck = b2 & 31;             // 16 o-tiles x 32 kc-tiles
    int o0 = ro * 64, kc0 = ck * 64;
    int k = kc0 >> 10, h0 = kc0 & 1023;
    int e = k ? s.i1 : s.i0;
    scale = k ? s.g1 : s.g0;
    src = Wo + (size_t)e * 1024 * 1024 + (size_t)h0 * 1024 + o0; // [r=hh][c=o]
    dst = WoT; dld = 2048; dr0 = o0; dc0 = kc0;
  }
  const int tid = threadIdx.x;
#pragma unroll
  for (int j = 0; j < 4; ++j) {
    int lin = j * 256 + tid;
    int r = lin >> 4, c4 = (lin & 15) * 4;
    float4 v = *(const float4*)&src[(size_t)r * 1024 + c4];
    tile[r][c4] = v.x; tile[r][c4 + 1] = v.y; tile[r][c4 + 2] = v.z; tile[r][c4 + 3] = v.w;
  }
  __syncthreads();
#pragma unroll
  for (int j = 0; j < 4; ++j) {
    int lin = j * 256 + tid;
    int r2 = lin >> 4, c2 = (lin & 15) * 4;     // r2: out row, c2: out col
    ushort4 o;
    o.x = f2bf(scale * tile[c2][r2]);
    o.y = f2bf(scale * tile[c2 + 1][r2]);
    o.z = f2bf(scale * tile[c2 + 2][r2]);
    o.w = f2bf(scale * tile[c2 + 3][r2]);
    *(ushort4*)&dst[(size_t)(dr0 + r2) * dld + dc0 + c2] = o;
  }
}

// ---------------------------------------------------------------------------
// bf16 GEMM, B pre-transposed ([N][K]). m97 structure: 128x128 tile, BK=64,
// 4 waves (2x2), 16x16x32 MFMA, global_load_lds width 16, 2-barrier K-loop.
// C = act(A @ Bt^T + bias)
// ---------------------------------------------------------------------------
template <int RELU, typename OUTT>
__global__ __launch_bounds__(256) void gemm_bt(
    const u16* __restrict__ A, const u16* __restrict__ Bt,
    const float* __restrict__ bias, OUTT* __restrict__ C, int N, int K) {
  __shared__ u16 smA[128 * 64];
  __shared__ u16 smB[128 * 64];
  const int tid = threadIdx.x;
  const int wave = tid >> 6, lane = tid & 63;
  const int m0 = blockIdx.y * 128, n0 = blockIdx.x * 128;
  const int wm = wave >> 1, wn = wave & 1;

  f32x4 acc[4][4] = {};

  const u16* gA = A + (size_t)(m0 + wave * 8 + (lane >> 3)) * K + (lane & 7) * 8;
  const u16* gB = Bt + (size_t)(n0 + wave * 8 + (lane >> 3)) * K + (lane & 7) * 8;
  u16* lA = smA + wave * 512;   // wave-uniform LDS staging base
  u16* lB = smB + wave * 512;

  for (int kt = 0; kt < K; kt += 64) {
#pragma unroll
    for (int j = 0; j < 4; ++j) {
      async16(gA + (size_t)j * 32 * K + kt, lA + j * 2048);
      async16(gB + (size_t)j * 32 * K + kt, lB + j * 2048);
    }
    __syncthreads();                      // drains vmcnt: tiles ready
#pragma unroll
    for (int kk = 0; kk < 2; ++kk) {
      bf16x8 af[4], bfr[4];
#pragma unroll
      for (int m = 0; m < 4; ++m)
        af[m] = *(const bf16x8*)(smA + (wm * 64 + m * 16 + (lane & 15)) * 64 +
                                 kk * 32 + (lane >> 4) * 8);
#pragma unroll
      for (int n = 0; n < 4; ++n)
        bfr[n] = *(const bf16x8*)(smB + (wn * 64 + n * 16 + (lane & 15)) * 64 +
                                  kk * 32 + (lane >> 4) * 8);
#pragma unroll
      for (int m = 0; m < 4; ++m)
#pragma unroll
        for (int n = 0; n < 4; ++n)
          acc[m][n] = __builtin_amdgcn_mfma_f32_16x16x32_bf16(af[m], bfr[n], acc[m][n], 0, 0, 0);
    }
    __syncthreads();                      // all reads done before next stage
  }

  const int r0 = m0 + wm * 64 + (lane >> 4) * 4;
  const int c0 = n0 + wn * 64 + (lane & 15);
#pragma unroll
  for (int n = 0; n < 4; ++n) {
    int col = c0 + n * 16;
    float bv = bias[col];
#pragma unroll
    for (int m = 0; m < 4; ++m) {
#pragma unroll
      for (int r = 0; r < 4; ++r) {
        int row = r0 + m * 16 + r;
        float v = acc[m][n][r] + bv;
        if (RELU) v = fmaxf(v, 0.f);
        if constexpr (sizeof(OUTT) == 2)
          C[(size_t)row * N + col] = f2bf(v);
        else
          C[(size_t)row * N + col] = v;
      }
    }
  }
}

// ---------------------------------------------------------------------------
extern "C" void kernel_launch(void* const* d_in, const int* in_sizes, int n_in,
                              void* d_out, int out_size, void* d_ws, size_t ws_size,
                              hipStream_t stream) {
  const float* x     = (const float*)d_in[0];
  const float* noise = (const float*)d_in[1];
  const float* gw    = (const float*)d_in[2];
  const float* gn    = (const float*)d_in[3];
  const float* Wi    = (const float*)d_in[4];
  const float* bi    = (const float*)d_in[5];
  const float* Wo    = (const float*)d_in[6];
  const float* bo    = (const float*)d_in[7];
  float* out = (float*)d_out;

  char* w = (char*)d_ws;
  float* part_sp = (float*)(w + 0x000000);       //  64 KB: [256][64]
  float* part_sx = (float*)(w + 0x010000);       //   1 MB: [256][1024]
  Sel*   sel     = (Sel*)  (w + 0x110000);       //   16 B
  float* bi_comb = (float*)(w + 0x110100);       //   8 KB
  float* bo_comb = (float*)(w + 0x112100);       //   4 KB
  u16*   gnT     = (u16*)  (w + 0x120000);       // 128 KB: [64][1024]
  float* p2_sx   = (float*)(w + 0x140000);       // 128 KB: [32][1024]
  float* p2_sp   = (float*)(w + 0x160000);       //   8 KB: [32][64]
  u16*   xb      = (u16*)  (w + 0x0200000);      //  32 MB: [16384][1024]
  u16*   WiT     = (u16*)  (w + 0x2200000);      //   4 MB: [2048][1024]
  u16*   WoT     = (u16*)  (w + 0x2600000);      //   4 MB: [1024][2048]
  u16*   h       = (u16*)  (w + 0x2A00000);      //  64 MB: [16384][2048]

  cvt_x_gn<<<272, 256, 0, stream>>>(x, gn, xb, gnT);
  gate_mfma<<<256, 256, 0, stream>>>(xb, gnT, part_sp, part_sx);
  reduce_parts<<<32, 256, 0, stream>>>(part_sp, part_sx, p2_sp, p2_sx);
  select_kernel<<<1, 256, 0, stream>>>(p2_sp, p2_sx, gw, noise, bi, bo,
                                       sel, bi_comb, bo_comb);
  prep_weights<<<1024, 256, 0, stream>>>(Wi, Wo, sel, WiT, WoT);
  gemm_bt<1, u16>  <<<dim3(16, 128), 256, 0, stream>>>(xb, WiT, bi_comb, h, 2048, 1024);
  gemm_bt<0, float><<<dim3(8, 128), 256, 0, stream>>>(h, WoT, bo_comb, out, 1024, 2048);
}